// Round 3
// baseline (95.804 us; speedup 1.0000x reference)
//
#include <hip/hip_runtime.h>
#include <hip/hip_bf16.h>

typedef __attribute__((ext_vector_type(4))) float f32x4;
typedef __attribute__((ext_vector_type(8))) short bf16x8;

#define HW    16384   // 128*128
#define CDIM  256
#define PITCH 80      // LDS row pitch in bytes (32 k * 2B = 64B data + 16B skew)
#define BOFF  40960   // B-tile LDS offset (A: 512 rows * 80B)

__device__ __forceinline__ unsigned short f2bf(float x) {
    union { float f; unsigned u; } c; c.f = x;
    unsigned r = c.u + 0x7fffu + ((c.u >> 16) & 1u);   // RNE
    return (unsigned short)(r >> 16);
}
__device__ __forceinline__ float bf2f(unsigned short u) {
    union { unsigned u; float f; } c; c.u = ((unsigned)u) << 16;
    return c.f;
}

// F2t[pixel][c] = sum_k W1[c,k] * feat[k][pixel]  (bf16 out, channel-last)
// BM=512 px, BN=128 c (2 n-halves, L3 absorbs feat re-read), BK=32, 8 K-steps.
// Per-instruction global A reads: 64 lanes x 16B = 1KB contiguous per channel.
// LDS: pitch-80 rows, k-slot XOR by (row>>4)&3 -> verified conflict-free on
// staging writes and b128 fragment reads.
__global__ __launch_bounds__(512, 2) void f2_gemm(
    const float* __restrict__ feat, const float* __restrict__ W1,
    unsigned short* __restrict__ f2t) {
    __shared__ char ldsc[51200];    // A [512][80], B at 40960: [128][80]

    const int t      = threadIdx.x;
    const int m_tile = blockIdx.x & 255;
    const int n_half = blockIdx.x >> 8;           // n-major dispatch
    const int m_base = m_tile << 9;               // 512 px, never straddles an image
    const float* fb  = feat + (size_t)(m_base >> 14) * CDIM * HW + (m_base & (HW - 1));
    const float* wb  = W1 + (size_t)(n_half * 128) * CDIM;

    const int lane = t & 63;
    const int wid  = t >> 6;
    const int wm   = wid >> 1;      // 4 m-slabs of 128 px
    const int wn   = wid & 1;       // 2 c-slabs of 64
    const int kg   = lane >> 4;     // k-slot 0..3 (8 k each)
    const int rr   = lane & 15;

    const int qa  = t & 127;        // A staging: px-quad 0..127
    const int ksa = t >> 7;         // A staging: k-slot 0..3
    const int cbr = t >> 2;         // B staging: c-row 0..127
    const int ksb = t & 3;          // B staging: k-slot 0..3

    f32x4 acc[8][4] = {};           // [mi][ni], D[c][px] orientation
    float av[8][4];                 // A raw: [dk][px-in-quad]
    float bv[8];                    // B raw: 8 k floats

    auto load_tile = [&](int kk) {
        const float* fk = fb + (size_t)(kk * 32 + ksa * 8) * HW + qa * 4;
#pragma unroll
        for (int dk = 0; dk < 8; ++dk) {
            const float4 v = *reinterpret_cast<const float4*>(fk + (size_t)dk * HW);
            av[dk][0] = v.x; av[dk][1] = v.y; av[dk][2] = v.z; av[dk][3] = v.w;
        }
        const float* wk = wb + (size_t)cbr * CDIM + kk * 32 + ksb * 8;
        const float4 u = *reinterpret_cast<const float4*>(wk);
        const float4 w = *reinterpret_cast<const float4*>(wk + 4);
        bv[0] = u.x; bv[1] = u.y; bv[2] = u.z; bv[3] = u.w;
        bv[4] = w.x; bv[5] = w.y; bv[6] = w.z; bv[7] = w.w;
    };

    auto write_tile = [&]() {
#pragma unroll
        for (int dm = 0; dm < 4; ++dm) {          // A: transpose in regs
            const int row = qa * 4 + dm;
            bf16x8 w;
#pragma unroll
            for (int dk = 0; dk < 8; ++dk) w[dk] = (short)f2bf(av[dk][dm]);
            *reinterpret_cast<bf16x8*>(
                ldsc + row * PITCH + ((ksa ^ ((row >> 4) & 3)) << 4)) = w;
        }
        {
            bf16x8 w;
#pragma unroll
            for (int dk = 0; dk < 8; ++dk) w[dk] = (short)f2bf(bv[dk]);
            *reinterpret_cast<bf16x8*>(
                ldsc + BOFF + cbr * PITCH + ((ksb ^ ((cbr >> 4) & 3)) << 4)) = w;
        }
    };

    auto compute = [&]() {
        bf16x8 af[8], bfv[4];
#pragma unroll
        for (int mi = 0; mi < 8; ++mi) {
            const int row = wm * 128 + mi * 16 + rr;
            af[mi] = *reinterpret_cast<const bf16x8*>(
                ldsc + row * PITCH + ((kg ^ ((row >> 4) & 3)) << 4));
        }
#pragma unroll
        for (int ni = 0; ni < 4; ++ni) {
            const int c = wn * 64 + ni * 16 + rr;
            bfv[ni] = *reinterpret_cast<const bf16x8*>(
                ldsc + BOFF + c * PITCH + ((kg ^ ((c >> 4) & 3)) << 4));
        }
#pragma unroll
        for (int mi = 0; mi < 8; ++mi)
#pragma unroll
            for (int ni = 0; ni < 4; ++ni)
                acc[mi][ni] = __builtin_amdgcn_mfma_f32_16x16x32_bf16(
                    bfv[ni], af[mi], acc[mi][ni], 0, 0, 0);   // D[c][px]
    };

    load_tile(0);
    write_tile();
    __syncthreads();
#pragma unroll
    for (int kk = 0; kk < 8; ++kk) {
        if (kk < 7) load_tile(kk + 1);    // T14: issue next loads before compute
        compute();
        __syncthreads();
        if (kk < 7) { write_tile(); __syncthreads(); }
    }

    // Epilogue: lane holds 4 consecutive channels (D[c][px]) -> packed 8B stores.
#pragma unroll
    for (int mi = 0; mi < 8; ++mi) {
        const int px = m_base + wm * 128 + mi * 16 + rr;
        unsigned short* dst = f2t + (size_t)px * CDIM + n_half * 128 + wn * 64 + kg * 4;
#pragma unroll
        for (int ni = 0; ni < 4; ++ni) {
            uint2 v;
            v.x = (unsigned)f2bf(acc[mi][ni][0]) | ((unsigned)f2bf(acc[mi][ni][1]) << 16);
            v.y = (unsigned)f2bf(acc[mi][ni][2]) | ((unsigned)f2bf(acc[mi][ni][3]) << 16);
            *reinterpret_cast<uint2*>(dst + ni * 16) = v;
        }
    }
}

// One wave per sample point: bilinear-weighted sum of 4 contiguous 512B rows
// of F2t, then relu(s+b1) . W2 -> 2 scalars, out = batch_edges + d.
__global__ __launch_bounds__(256) void point_kernel(
    const unsigned short* __restrict__ f2t,
    const float* __restrict__ be,
    const float* __restrict__ b1, const float* __restrict__ W2,
    float* __restrict__ out) {
    const int p    = (blockIdx.x * 256 + threadIdx.x) >> 6;   // 0..65535
    const int lane = threadIdx.x & 63;

    const float ex = be[p * 2 + 0];
    const float ey = be[p * 2 + 1];
    const float gx = ex * (2.0f / 128.0f) - 1.0f;
    const float gy = ey * (2.0f / 128.0f) - 1.0f;
    const float px = (gx + 1.0f) * 64.0f - 0.5f;
    const float py = (gy + 1.0f) * 64.0f - 0.5f;
    const float x0f = floorf(px), y0f = floorf(py);
    const int   x0 = (int)x0f, y0 = (int)y0f;
    const float wx1 = px - x0f, wy1 = py - y0f;
    const float wx0 = 1.0f - wx1, wy0 = 1.0f - wy1;

    const size_t pix_base = (size_t)(p >> 13) * HW;
    const int c0 = lane * 4;

    float s0 = 0.f, s1 = 0.f, s2 = 0.f, s3 = 0.f;
#pragma unroll
    for (int cy = 0; cy < 2; ++cy) {
        const int   yi  = y0 + cy;
        const float wy  = cy ? wy1 : wy0;
        const bool  yin = (yi >= 0) && (yi < 128);
        const int   yc  = min(max(yi, 0), 127);
#pragma unroll
        for (int cx = 0; cx < 2; ++cx) {
            const int   xi  = x0 + cx;
            const float wx  = cx ? wx1 : wx0;
            const bool  xin = (xi >= 0) && (xi < 128);
            const int   xc  = min(max(xi, 0), 127);
            const float w   = wx * wy * (float)(xin && yin);
            const ushort4 v = *reinterpret_cast<const ushort4*>(
                &f2t[(pix_base + (size_t)yc * 128 + xc) * 256 + c0]);
            s0 += w * bf2f(v.x); s1 += w * bf2f(v.y);
            s2 += w * bf2f(v.z); s3 += w * bf2f(v.w);
        }
    }
    const float4 bb  = *reinterpret_cast<const float4*>(&b1[c0]);
    const float4 w2a = *reinterpret_cast<const float4*>(&W2[c0]);
    const float4 w2b = *reinterpret_cast<const float4*>(&W2[256 + c0]);
    const float h0 = fmaxf(s0 + bb.x, 0.f);
    const float h1 = fmaxf(s1 + bb.y, 0.f);
    const float h2 = fmaxf(s2 + bb.z, 0.f);
    const float h3 = fmaxf(s3 + bb.w, 0.f);
    float a0 = h0 * w2a.x + h1 * w2a.y + h2 * w2a.z + h3 * w2a.w;
    float a1 = h0 * w2b.x + h1 * w2b.y + h2 * w2b.z + h3 * w2b.w;
#pragma unroll
    for (int off = 32; off > 0; off >>= 1) {
        a0 += __shfl_xor(a0, off);
        a1 += __shfl_xor(a1, off);
    }
    if (lane == 0) {
        out[p * 2 + 0] = ex + a0;
        out[p * 2 + 1] = ey + a1;
    }
}

extern "C" void kernel_launch(void* const* d_in, const int* in_sizes, int n_in,
                              void* d_out, int out_size, void* d_ws, size_t ws_size,
                              hipStream_t stream) {
    const float* feat = (const float*)d_in[0];
    const float* be   = (const float*)d_in[1];
    const float* W1   = (const float*)d_in[2];
    const float* b1   = (const float*)d_in[3];
    const float* W2   = (const float*)d_in[4];
    float* out = (float*)d_out;
    unsigned short* f2t = (unsigned short*)d_ws;   // 131072*256 bf16 = 64 MiB

    f2_gemm<<<512, 512, 0, stream>>>(feat, W1, f2t);
    point_kernel<<<16384, 256, 0, stream>>>(f2t, be, b1, W2, out);
}